// Round 2
// baseline (118.643 us; speedup 1.0000x reference)
//
#include <hip/hip_runtime.h>

#define L 4096
#define NT 256
#define PPT 16
// Pad 2 words per 16 bins: stride 18 per segment -> every thread's 16-bin
// scan segment is 8B-aligned (72*tid bytes) => ds_read/write_b64, and the
// b64 lane->bank map is uniform (4 word-accesses/bank = optimal).
__device__ __forceinline__ int PIDX(int p) { return p + 2 * (p >> 4); }
#define PADSZ (L + 2 * (L / 16))  // 4608 words = 18 KB

typedef float f32x4 __attribute__((ext_vector_type(4)));  // native vec for nontemporal

// x += dpp_move(x); invalid source lanes contribute 0 (old = 0).
template <int CTRL, int RM>
__device__ __forceinline__ unsigned dpp_add(unsigned x) {
  return x + (unsigned)__builtin_amdgcn_update_dpp(0, (int)x, CTRL, RM, 0xF, false);
}
template <int CTRL, int RM>
__device__ __forceinline__ float dpp_addf(float x) {
  int m = __builtin_amdgcn_update_dpp(0, __float_as_int(x), CTRL, RM, 0xF, false);
  return x + __int_as_float(m);
}
// Wave64 inclusive +scan, pure VALU (no LDS pipe). Lane 63 holds the total.
__device__ __forceinline__ unsigned wave_incl_scan(unsigned x) {
  x = dpp_add<0x111, 0xF>(x);   // row_shr:1
  x = dpp_add<0x112, 0xF>(x);   // row_shr:2
  x = dpp_add<0x114, 0xF>(x);   // row_shr:4
  x = dpp_add<0x118, 0xF>(x);   // row_shr:8
  x = dpp_add<0x142, 0xA>(x);   // row_bcast:15 -> rows 1,3
  x = dpp_add<0x143, 0xC>(x);   // row_bcast:31 -> rows 2,3
  return x;
}
__device__ __forceinline__ float wave_incl_scanf(float x) {
  x = dpp_addf<0x111, 0xF>(x);
  x = dpp_addf<0x112, 0xF>(x);
  x = dpp_addf<0x114, 0xF>(x);
  x = dpp_addf<0x118, 0xF>(x);
  x = dpp_addf<0x142, 0xA>(x);
  x = dpp_addf<0x143, 0xC>(x);
  return x;
}

// ASCENDING gaussian-equidistributed 12-bit key (larger label -> larger key).
__device__ __forceinline__ int label_key12(float x) {
  float t = x * __builtin_amdgcn_rcpf(1.0f + fabsf(x));
  int k = (int)fmaf(t, 2048.0f, 2048.0f);
  return min(4095, max(0, k));
}

// Per row: loss_row = sum_i ln(c_i) - sum preds, c_i = P[key_i] - pfx_i,
// P = prefix-inclusive sum of fixed-point (2^18) weight histogram,
// pfx_i = ds_add_rtn_u32 return (same-bin weights that arrived earlier).
// One row per block: grid = B = 2048 -> exactly 8 blocks/CU resident
// (LDS 18.1 KB * 8 = 148 KB; waves_per_eu(8) caps VGPR at 64).
__global__ __launch_bounds__(NT) __attribute__((amdgpu_waves_per_eu(8)))
void listmle_kernel(const float* __restrict__ preds,
                    const float* __restrict__ labels,
                    float* __restrict__ out, float invB) {
  __shared__ __align__(16) unsigned hist[PADSZ];  // 18 KB, per-row histogram
  __shared__ float wsum4[4];      // per-wave pred sums
  __shared__ unsigned wscan4[4];  // per-wave scan totals
  __shared__ float wlog4[4];      // per-wave log2 sums

  const int tid = threadIdx.x;
  const int lane = tid & 63;
  const int wave = tid >> 6;
  const size_t row = blockIdx.x;

  // ---- zero hist: each thread owns its 18-word segment (9 x b64) ----
  {
    uint2* zs = reinterpret_cast<uint2*>(&hist[18 * tid]);
#pragma unroll
    for (int e = 0; e < 9; ++e) zs[e] = make_uint2(0u, 0u);
  }

  // ---- issue the row's loads (perfectly coalesced, streaming) ----
  const f32x4* p4 = reinterpret_cast<const f32x4*>(preds + row * L);
  const f32x4* l4 = reinterpret_cast<const f32x4*>(labels + row * L);
  f32x4 pv[4], lv[4];
#pragma unroll
  for (int q = 0; q < 4; ++q) {
    pv[q] = __builtin_nontemporal_load(p4 + tid + NT * q);
    lv[q] = __builtin_nontemporal_load(l4 + tid + NT * q);
  }
  __syncthreads();  // b1: hist zeroed (also drains the loads - fine)

  // ---- phase 1: fixed-point weight histogram; rtn = my in-bin prefix ----
  float lsum = 0.0f;
  unsigned pfx[PPT];
  unsigned kp[PPT / 2];
#pragma unroll
  for (int q = 0; q < 4; ++q) {
#pragma unroll
    for (int j = 0; j < 4; ++j) {
      const int e = q * 4 + j;
      float p = pv[q][j];
      lsum += p;
      int key = label_key12(lv[q][j]);
      if ((j & 1) == 0) kp[e >> 1] = (unsigned)key;
      else kp[e >> 1] |= (unsigned)key << 16;
      // exp(p)*2^18 in ONE v_exp: exp2(p*log2e + 18)
      unsigned wu = (unsigned)(__builtin_amdgcn_exp2f(
                        fmaf(p, 1.44269504089f, 18.0f)) + 0.5f);
      pfx[e] = atomicAdd(&hist[PIDX(key)], wu);  // native ds_add_rtn_u32
    }
  }
  {
    float si = wave_incl_scanf(lsum);  // DPP, no LDS pipe
    if (lane == 63) wsum4[wave] = si;
  }
  __syncthreads();  // b2: histogram + wave sums complete

  // ---- phase 2: prefix-inclusive scan over 4096 bins (in-place, b64) ----
  {
    uint2* seg = reinterpret_cast<uint2*>(&hist[18 * tid]);
    uint2 v[8];
    unsigned tot = 0;
#pragma unroll
    for (int e = 0; e < 8; ++e) {
      v[e] = seg[e];
      tot += v[e].x + v[e].y;
    }
    unsigned incl = wave_incl_scan(tot);
    if (lane == 63) wscan4[wave] = incl;
    __syncthreads();  // b3: wave scan totals
    unsigned run = incl - tot;
#pragma unroll
    for (int w = 0; w < 4; ++w)
      if (w < wave) run += wscan4[w];  // wave-uniform predicate
#pragma unroll
    for (int e = 0; e < 8; ++e) {
      unsigned a = run + v[e].x;
      unsigned b = a + v[e].y;
      seg[e] = make_uint2(a, b);  // P[bin], inclusive
      run = b;
    }
  }
  __syncthreads();  // b4: P published

  // ---- phase 3: c_i = P[key_i] - pfx_i (exact u32); sum log2 ----
  float slog2 = 0.0f;
#pragma unroll
  for (int e = 0; e < PPT; ++e) {
    unsigned key = (kp[e >> 1] >> ((e & 1) * 16)) & 0xFFFu;
    unsigned c = hist[PIDX((int)key)] - pfx[e];
    slog2 += __log2f((float)c);
  }
  {
    float si = wave_incl_scanf(slog2);  // DPP
    if (lane == 63) wlog4[wave] = si;
  }
  __syncthreads();  // b5: wlog/wsum ready
  if (tid == 0) {
    float t = wlog4[0] + wlog4[1] + wlog4[2] + wlog4[3];
    float S = wsum4[0] + wsum4[1] + wsum4[2] + wsum4[3];
    // sum ln c = ln2 * (sum log2 c_fixed - L*18); rowval = that - S
    float rowval = 0.69314718056f * (t - (float)(L * 18)) - S;
    atomicAdd(out, rowval * invB);
  }
}

extern "C" void kernel_launch(void* const* d_in, const int* in_sizes, int n_in,
                              void* d_out, int out_size, void* d_ws, size_t ws_size,
                              hipStream_t stream) {
  const float* preds = (const float*)d_in[0];
  const float* labels = (const float*)d_in[1];
  float* out = (float*)d_out;
  const int B = in_sizes[0] / L;

  (void)hipMemsetAsync(d_out, 0, sizeof(float), stream);  // graph-capture safe
  listmle_kernel<<<B, NT, 0, stream>>>(preds, labels, out, 1.0f / (float)B);
}

// Round 3
// 113.129 us; speedup vs baseline: 1.0487x; 1.0487x over previous
//
#include <hip/hip_runtime.h>

#define L 4096
#define NT 256
#define PPT 16
// Pad 2 words per 16 bins: stride 18 per segment -> every thread's 16-bin
// scan segment is 8B-aligned (72*tid bytes) => ds_read/write_b64; the b64
// lane->bank map is uniform (4 word-accesses/bank = the wave64 b64 floor).
__device__ __forceinline__ int PIDX(int p) { return p + 2 * (p >> 4); }
#define PADSZ (L + 2 * (L / 16))  // 4608 words = 18 KB

typedef float f32x4 __attribute__((ext_vector_type(4)));

// x += dpp_move(x); invalid source lanes contribute 0 (old = 0).
template <int CTRL, int RM>
__device__ __forceinline__ unsigned dpp_add(unsigned x) {
  return x + (unsigned)__builtin_amdgcn_update_dpp(0, (int)x, CTRL, RM, 0xF, false);
}
template <int CTRL, int RM>
__device__ __forceinline__ float dpp_addf(float x) {
  int m = __builtin_amdgcn_update_dpp(0, __float_as_int(x), CTRL, RM, 0xF, false);
  return x + __int_as_float(m);
}
// Wave64 inclusive +scan, pure VALU (no LDS pipe). Lane 63 holds the total.
__device__ __forceinline__ unsigned wave_incl_scan(unsigned x) {
  x = dpp_add<0x111, 0xF>(x);   // row_shr:1
  x = dpp_add<0x112, 0xF>(x);   // row_shr:2
  x = dpp_add<0x114, 0xF>(x);   // row_shr:4
  x = dpp_add<0x118, 0xF>(x);   // row_shr:8
  x = dpp_add<0x142, 0xA>(x);   // row_bcast:15 -> rows 1,3
  x = dpp_add<0x143, 0xC>(x);   // row_bcast:31 -> rows 2,3
  return x;
}
__device__ __forceinline__ float wave_incl_scanf(float x) {
  x = dpp_addf<0x111, 0xF>(x);
  x = dpp_addf<0x112, 0xF>(x);
  x = dpp_addf<0x114, 0xF>(x);
  x = dpp_addf<0x118, 0xF>(x);
  x = dpp_addf<0x142, 0xA>(x);
  x = dpp_addf<0x143, 0xC>(x);
  return x;
}

// ASCENDING gaussian-equidistributed 12-bit key (larger label -> larger key).
__device__ __forceinline__ int label_key12(float x) {
  float t = x * __builtin_amdgcn_rcpf(1.0f + fabsf(x));
  int k = (int)fmaf(t, 2048.0f, 2048.0f);
  return min(4095, max(0, k));
}

// Per row: loss_row = sum_i ln(c_i) - sum preds, c_i = P[key_i] - pfx_i,
// P = prefix-inclusive sum of fixed-point (2^18) weight histogram,
// pfx_i = ds_add_rtn_u32 return (same-bin weights that arrived earlier).
//
// One row per block, grid = B = 2048. Inputs are folded to packed keys
// (kp[8]) and fixed-point weights (wu[16]) IMMEDIATELY at load so the
// float4 staging regs die before phase 1 -> natural peak ~50 VGPR ->
// 8 waves/EU without spills (waves_per_eu(4,8): min 4 never forces a
// spill; max 8 lets the scheduler pack 8 blocks/CU; LDS 8x18.1KB=148KB).
// Plain (cached) loads: inputs are L3-resident across bench iterations.
__global__ __launch_bounds__(NT) __attribute__((amdgpu_waves_per_eu(4, 8)))
void listmle_kernel(const float* __restrict__ preds,
                    const float* __restrict__ labels,
                    float* __restrict__ out, float invB) {
  __shared__ __align__(16) unsigned hist[PADSZ];  // 18 KB, per-row histogram
  __shared__ float wsum4[4];      // per-wave pred sums
  __shared__ unsigned wscan4[4];  // per-wave scan totals
  __shared__ float wlog4[4];      // per-wave log2 sums

  const int tid = threadIdx.x;
  const int lane = tid & 63;
  const int wave = tid >> 6;
  const size_t row = blockIdx.x;

  // ---- issue the row's loads first (coalesced, long latency) ----
  const f32x4* p4 = reinterpret_cast<const f32x4*>(preds + row * L);
  const f32x4* l4 = reinterpret_cast<const f32x4*>(labels + row * L);
  f32x4 pv[4], lv[4];
#pragma unroll
  for (int q = 0; q < 4; ++q) {
    pv[q] = p4[tid + NT * q];
    lv[q] = l4[tid + NT * q];
  }

  // ---- zero hist: each thread owns its 18-word segment (9 x b64) ----
  {
    uint2* zs = reinterpret_cast<uint2*>(&hist[18 * tid]);
#pragma unroll
    for (int e = 0; e < 9; ++e) zs[e] = make_uint2(0u, 0u);
  }

  // ---- fold inputs to minimal state BEFORE b1: kp[8], wu[16], lsum ----
  // (kills pv/lv 32 regs before the barrier-locked phases; v_exp work
  //  overlaps the zeroing + barrier instead of sitting inside phase 1)
  unsigned kp[PPT / 2];
  unsigned wu[PPT];
  float lsum = 0.0f;
#pragma unroll
  for (int q = 0; q < 4; ++q) {
#pragma unroll
    for (int j = 0; j < 4; ++j) {
      const int e = q * 4 + j;
      float p = pv[q][j];
      lsum += p;
      int key = label_key12(lv[q][j]);
      if ((e & 1) == 0) kp[e >> 1] = (unsigned)key;
      else kp[e >> 1] |= (unsigned)key << 16;
      // exp(p)*2^18 in ONE v_exp: exp2(p*log2e + 18)
      wu[e] = (unsigned)(__builtin_amdgcn_exp2f(
                  fmaf(p, 1.44269504089f, 18.0f)) + 0.5f);
    }
  }
  {
    float si = wave_incl_scanf(lsum);  // DPP, no LDS pipe
    if (lane == 63) wsum4[wave] = si;  // wsum4 untouched by zeroing
  }
  __syncthreads();  // b1: hist zeroed

  // ---- phase 1: histogram atomics only; rtn = my in-bin prefix ----
  unsigned pfx[PPT];
#pragma unroll
  for (int e = 0; e < PPT; ++e) {
    int key = (int)((kp[e >> 1] >> ((e & 1) * 16)) & 0xFFFu);
    pfx[e] = atomicAdd(&hist[PIDX(key)], wu[e]);  // native ds_add_rtn_u32
  }
  __syncthreads();  // b2: histogram complete

  // ---- phase 2: prefix-inclusive scan over 4096 bins (in-place, b64) ----
  {
    uint2* seg = reinterpret_cast<uint2*>(&hist[18 * tid]);
    uint2 v[8];
    unsigned tot = 0;
#pragma unroll
    for (int e = 0; e < 8; ++e) {
      v[e] = seg[e];
      tot += v[e].x + v[e].y;
    }
    unsigned incl = wave_incl_scan(tot);
    if (lane == 63) wscan4[wave] = incl;
    __syncthreads();  // b3: wave scan totals
    unsigned run = incl - tot;
#pragma unroll
    for (int w = 0; w < 4; ++w)
      if (w < wave) run += wscan4[w];  // wave-uniform predicate
#pragma unroll
    for (int e = 0; e < 8; ++e) {
      unsigned a = run + v[e].x;
      unsigned b = a + v[e].y;
      seg[e] = make_uint2(a, b);  // P[bin], inclusive
      run = b;
    }
  }
  __syncthreads();  // b4: P published

  // ---- phase 3: c_i = P[key_i] - pfx_i (exact u32); sum log2 ----
  float slog2 = 0.0f;
#pragma unroll
  for (int e = 0; e < PPT; ++e) {
    unsigned key = (kp[e >> 1] >> ((e & 1) * 16)) & 0xFFFu;
    unsigned c = hist[PIDX((int)key)] - pfx[e];
    slog2 += __log2f((float)c);
  }
  {
    float si = wave_incl_scanf(slog2);  // DPP
    if (lane == 63) wlog4[wave] = si;
  }
  __syncthreads();  // b5: wlog/wsum ready
  if (tid == 0) {
    float t = wlog4[0] + wlog4[1] + wlog4[2] + wlog4[3];
    float S = wsum4[0] + wsum4[1] + wsum4[2] + wsum4[3];
    // sum ln c = ln2 * (sum log2 c_fixed - L*18); rowval = that - S
    float rowval = 0.69314718056f * (t - (float)(L * 18)) - S;
    atomicAdd(out, rowval * invB);
  }
}

extern "C" void kernel_launch(void* const* d_in, const int* in_sizes, int n_in,
                              void* d_out, int out_size, void* d_ws, size_t ws_size,
                              hipStream_t stream) {
  const float* preds = (const float*)d_in[0];
  const float* labels = (const float*)d_in[1];
  float* out = (float*)d_out;
  const int B = in_sizes[0] / L;

  (void)hipMemsetAsync(d_out, 0, sizeof(float), stream);  // graph-capture safe
  listmle_kernel<<<B, NT, 0, stream>>>(preds, labels, out, 1.0f / (float)B);
}

// Round 4
// 101.880 us; speedup vs baseline: 1.1645x; 1.1104x over previous
//
#include <hip/hip_runtime.h>

#define L 4096
#define NT 256
#define PPT 16
#define RPB 2                 // rows per block (ping-pong hists, overlapped)
__device__ __forceinline__ int PIDX(int p) { return p + (p >> 4); }
#define PADSZ (L + L / 16)    // 4352 words = 17408 B per hist

// x += dpp_move(x); invalid source lanes contribute 0 (old = 0).
template <int CTRL, int RM>
__device__ __forceinline__ unsigned dpp_add(unsigned x) {
  return x + (unsigned)__builtin_amdgcn_update_dpp(0, (int)x, CTRL, RM, 0xF, false);
}
template <int CTRL, int RM>
__device__ __forceinline__ float dpp_addf(float x) {
  int m = __builtin_amdgcn_update_dpp(0, __float_as_int(x), CTRL, RM, 0xF, false);
  return x + __int_as_float(m);
}
// Wave64 inclusive +scan, pure VALU (no LDS pipe). Lane 63 holds the total.
__device__ __forceinline__ unsigned wave_incl_scan(unsigned x) {
  x = dpp_add<0x111, 0xF>(x);   // row_shr:1
  x = dpp_add<0x112, 0xF>(x);   // row_shr:2
  x = dpp_add<0x114, 0xF>(x);   // row_shr:4
  x = dpp_add<0x118, 0xF>(x);   // row_shr:8
  x = dpp_add<0x142, 0xA>(x);   // row_bcast:15 -> rows 1,3
  x = dpp_add<0x143, 0xC>(x);   // row_bcast:31 -> rows 2,3
  return x;
}
__device__ __forceinline__ float wave_incl_scanf(float x) {
  x = dpp_addf<0x111, 0xF>(x);
  x = dpp_addf<0x112, 0xF>(x);
  x = dpp_addf<0x114, 0xF>(x);
  x = dpp_addf<0x118, 0xF>(x);
  x = dpp_addf<0x142, 0xA>(x);
  x = dpp_addf<0x143, 0xC>(x);
  return x;
}

// ASCENDING gaussian-equidistributed 12-bit key (larger label -> larger key).
__device__ __forceinline__ int label_key12(float x) {
  float t = x * __builtin_amdgcn_rcpf(1.0f + fabsf(x));
  int k = (int)fmaf(t, 2048.0f, 2048.0f);
  return min(4095, max(0, k));
}

// Per row: loss_row = sum_i ln(c_i) - sum preds, c_i = P[key_i] - pfx_i,
// P = prefix-inclusive sum of fixed-point (2^18) weight histogram,
// pfx_i = ds_add_rtn_u32 return (same-bin weights that arrived earlier).
//
// Round-0 proven structure (RPB=2, stride-17 hist, exp interleaved with
// atomics) + ping-pong histograms: row 0 and row 1 use DISJOINT hists, so
// row0's phase 3 (LDS gather + log2, VALU-heavy) runs in the SAME
// barrier-free region as row1's phase 1 (ds_add_rtn + v_exp, DS-heavy).
// Barrier train: 10 -> 8, with one large overlap window.
// LDS 2x17408 + 64 = ~34.9 KB -> 4 blocks/CU (grid 1024 = exactly 4/CU).
__global__ __launch_bounds__(NT) __attribute__((amdgpu_waves_per_eu(2, 4)))
void listmle_kernel(const float* __restrict__ preds,
                    const float* __restrict__ labels,
                    float* __restrict__ out, float invB) {
  __shared__ unsigned hist[2][PADSZ];  // 34.8 KB, one hist per row
  __shared__ float wsum[2][4];         // per-row, per-wave pred sums
  __shared__ unsigned wscan4[4];       // per-wave scan totals (reused, guarded)
  __shared__ float wlog[2][4];         // per-row, per-wave log2 sums

  const int tid = threadIdx.x;
  const int lane = tid & 63;
  const int wave = tid >> 6;
  const size_t row0 = (size_t)blockIdx.x * RPB;

  // ---- prefetch both rows up front (one delivery window) ----
  float pe[RPB][PPT], le[RPB][PPT];
#pragma unroll
  for (int r = 0; r < RPB; ++r) {
    const float4* p4 = reinterpret_cast<const float4*>(preds + (row0 + r) * L) + tid * 4;
    const float4* l4 = reinterpret_cast<const float4*>(labels + (row0 + r) * L) + tid * 4;
#pragma unroll
    for (int q = 0; q < 4; ++q) {
      float4 p = p4[q], lb = l4[q];
      pe[r][q * 4 + 0] = p.x;  pe[r][q * 4 + 1] = p.y;
      pe[r][q * 4 + 2] = p.z;  pe[r][q * 4 + 3] = p.w;
      le[r][q * 4 + 0] = lb.x; le[r][q * 4 + 1] = lb.y;
      le[r][q * 4 + 2] = lb.z; le[r][q * 4 + 3] = lb.w;
    }
  }

  // ---- zero BOTH hists once (coalesced, conflict-free) ----
  {
    unsigned* hz = &hist[0][0];
    for (int k = tid; k < 2 * PADSZ; k += NT) hz[k] = 0u;
  }
  __syncthreads();  // B1: hists zeroed

  // ================= row 0, phase 1: exp+atomic into hist[0] =============
  float lsum0 = 0.0f;
  unsigned pfx0[PPT], kp0[PPT / 2];
#pragma unroll
  for (int e = 0; e < PPT; ++e) {
    float p = pe[0][e];
    lsum0 += p;
    int key = label_key12(le[0][e]);
    if ((e & 1) == 0) kp0[e >> 1] = (unsigned)key;
    else kp0[e >> 1] |= (unsigned)key << 16;
    // exp(p)*2^18 in ONE v_exp: exp2(p*log2e + 18)
    unsigned wu = (unsigned)(__builtin_amdgcn_exp2f(
                      fmaf(p, 1.44269504089f, 18.0f)) + 0.5f);
    pfx0[e] = atomicAdd(&hist[0][PIDX(key)], wu);  // native ds_add_rtn_u32
  }
  {
    float si = wave_incl_scanf(lsum0);  // DPP, no LDS pipe
    if (lane == 63) wsum[0][wave] = si;
  }
  __syncthreads();  // B2: hist[0] complete

  // ================= row 0, phase 2: prefix scan of hist[0] ==============
  {
    unsigned h[PPT], tot = 0;
#pragma unroll
    for (int e = 0; e < PPT; ++e) {
      tot += hist[0][PIDX(tid * PPT + e)];
      h[e] = tot;
    }
    unsigned incl = wave_incl_scan(tot);
    if (lane == 63) wscan4[wave] = incl;
    __syncthreads();  // B3: wave scan totals (row 0)
    unsigned base = incl - tot;
#pragma unroll
    for (int w = 0; w < 4; ++w)
      if (w < wave) base += wscan4[w];  // wave-uniform predicate
#pragma unroll
    for (int e = 0; e < PPT; ++e)
      hist[0][PIDX(tid * PPT + e)] = base + h[e];  // P0[bin], inclusive
  }
  __syncthreads();  // B4: P0 published

  // ======== OVERLAP WINDOW: row 1 phase 1  ||  row 0 phase 3 =============
  // Disjoint hists: hist[1] atomics (DS+v_exp) and hist[0] gathers+log2
  // (DS+VALU) share no data -> no barrier, scheduler interleaves freely.
  float lsum1 = 0.0f;
  unsigned pfx1[PPT], kp1[PPT / 2];
#pragma unroll
  for (int e = 0; e < PPT; ++e) {
    float p = pe[1][e];
    lsum1 += p;
    int key = label_key12(le[1][e]);
    if ((e & 1) == 0) kp1[e >> 1] = (unsigned)key;
    else kp1[e >> 1] |= (unsigned)key << 16;
    unsigned wu = (unsigned)(__builtin_amdgcn_exp2f(
                      fmaf(p, 1.44269504089f, 18.0f)) + 0.5f);
    pfx1[e] = atomicAdd(&hist[1][PIDX(key)], wu);
  }
  float slog0 = 0.0f;
#pragma unroll
  for (int e = 0; e < PPT; ++e) {
    unsigned key = (kp0[e >> 1] >> ((e & 1) * 16)) & 0xFFFu;
    unsigned c = hist[0][PIDX((int)key)] - pfx0[e];
    slog0 += __log2f((float)c);
  }
  {
    float s1 = wave_incl_scanf(lsum1);
    if (lane == 63) wsum[1][wave] = s1;
    float s0 = wave_incl_scanf(slog0);
    if (lane == 63) wlog[0][wave] = s0;
  }
  __syncthreads();  // B5: hist[1] complete; wlog[0]/wsum[1] written

  // ================= row 1, phase 2: prefix scan of hist[1] ==============
  {
    unsigned h[PPT], tot = 0;
#pragma unroll
    for (int e = 0; e < PPT; ++e) {
      tot += hist[1][PIDX(tid * PPT + e)];
      h[e] = tot;
    }
    unsigned incl = wave_incl_scan(tot);
    if (lane == 63) wscan4[wave] = incl;   // reuse: last read was before B4
    __syncthreads();  // B6: wave scan totals (row 1)
    unsigned base = incl - tot;
#pragma unroll
    for (int w = 0; w < 4; ++w)
      if (w < wave) base += wscan4[w];
#pragma unroll
    for (int e = 0; e < PPT; ++e)
      hist[1][PIDX(tid * PPT + e)] = base + h[e];  // P1[bin], inclusive
  }
  __syncthreads();  // B7: P1 published

  // ================= row 1, phase 3: gather + log2 ========================
  float slog1 = 0.0f;
#pragma unroll
  for (int e = 0; e < PPT; ++e) {
    unsigned key = (kp1[e >> 1] >> ((e & 1) * 16)) & 0xFFFu;
    unsigned c = hist[1][PIDX((int)key)] - pfx1[e];
    slog1 += __log2f((float)c);
  }
  {
    float si = wave_incl_scanf(slog1);
    if (lane == 63) wlog[1][wave] = si;
  }
  __syncthreads();  // B8: all wlog/wsum ready

  if (tid == 0) {
    float t = wlog[0][0] + wlog[0][1] + wlog[0][2] + wlog[0][3]
            + wlog[1][0] + wlog[1][1] + wlog[1][2] + wlog[1][3];
    float S = wsum[0][0] + wsum[0][1] + wsum[0][2] + wsum[0][3]
            + wsum[1][0] + wsum[1][1] + wsum[1][2] + wsum[1][3];
    // sum ln c = ln2 * (sum log2 c_fixed - 2*L*18); rows' total minus S
    float acc = 0.69314718056f * (t - (float)(2 * L * 18)) - S;
    atomicAdd(out, acc * invB);
  }
}

extern "C" void kernel_launch(void* const* d_in, const int* in_sizes, int n_in,
                              void* d_out, int out_size, void* d_ws, size_t ws_size,
                              hipStream_t stream) {
  const float* preds = (const float*)d_in[0];
  const float* labels = (const float*)d_in[1];
  float* out = (float*)d_out;
  const int B = in_sizes[0] / L;

  (void)hipMemsetAsync(d_out, 0, sizeof(float), stream);  // graph-capture safe
  listmle_kernel<<<B / RPB, NT, 0, stream>>>(preds, labels, out, 1.0f / (float)B);
}